// Round 1
// baseline (1631.150 us; speedup 1.0000x reference)
//
#include <hip/hip_runtime.h>
#include <cstdint>
#include <cmath>

typedef unsigned short u16;
typedef __attribute__((ext_vector_type(8))) short short8;
typedef __attribute__((ext_vector_type(4))) float f32x4;

#define BB 4
#define NTOK 4096
#define CDIM 512
#define NROWS (BB * NTOK)

__device__ __forceinline__ u16 f2bf(float f) {
  union { float f; uint32_t u; } v; v.f = f;
  return (u16)((v.u + 0x7fffu + ((v.u >> 16) & 1u)) >> 16);
}

__device__ __forceinline__ f32x4 mfma16(short8 a, short8 b, f32x4 c) {
  return __builtin_amdgcn_mfma_f32_16x16x32_bf16(a, b, c, 0, 0, 0);
}

__device__ __forceinline__ void gload16(const u16* g, u16* l) {
  __builtin_amdgcn_global_load_lds(
      (const __attribute__((address_space(1))) void*)g,
      (__attribute__((address_space(3))) void*)l, 16, 0, 0);
}

// ---------------- LayerNorm (one wave per row of 512) ----------------
__global__ __launch_bounds__(256) void ln_kernel(const float* __restrict__ x,
                                                 const float* __restrict__ gam,
                                                 const float* __restrict__ bet,
                                                 u16* __restrict__ hn) {
  int row = blockIdx.x * 4 + (threadIdx.x >> 6);
  int lane = threadIdx.x & 63;
  const float4* xr = (const float4*)(x + (size_t)row * CDIM);
  float4 a0 = xr[lane];
  float4 a1 = xr[lane + 64];
  float s = a0.x + a0.y + a0.z + a0.w + a1.x + a1.y + a1.z + a1.w;
  float ss = a0.x * a0.x + a0.y * a0.y + a0.z * a0.z + a0.w * a0.w +
             a1.x * a1.x + a1.y * a1.y + a1.z * a1.z + a1.w * a1.w;
#pragma unroll
  for (int j = 0; j < 6; ++j) {
    s += __shfl_xor(s, 1 << j);
    ss += __shfl_xor(ss, 1 << j);
  }
  float mu = s * (1.0f / CDIM);
  float var = ss * (1.0f / CDIM) - mu * mu;
  float rs = rsqrtf(var + 1e-3f);
  const float4* g4 = (const float4*)gam;
  const float4* b4 = (const float4*)bet;
  float4 g0 = g4[lane], g1 = g4[lane + 64];
  float4 c0 = b4[lane], c1 = b4[lane + 64];
  u16* out = hn + (size_t)row * CDIM;
  ushort4 o0, o1;
  o0.x = f2bf((a0.x - mu) * rs * g0.x + c0.x);
  o0.y = f2bf((a0.y - mu) * rs * g0.y + c0.y);
  o0.z = f2bf((a0.z - mu) * rs * g0.z + c0.z);
  o0.w = f2bf((a0.w - mu) * rs * g0.w + c0.w);
  o1.x = f2bf((a1.x - mu) * rs * g1.x + c1.x);
  o1.y = f2bf((a1.y - mu) * rs * g1.y + c1.y);
  o1.z = f2bf((a1.z - mu) * rs * g1.z + c1.z);
  o1.w = f2bf((a1.w - mu) * rs * g1.w + c1.w);
  *(ushort4*)(out + lane * 4) = o0;
  *(ushort4*)(out + 256 + lane * 4) = o1;
}

// ---------- weights: fp32 [K,N] -> bf16 W^T [N,K], 4 of them ----------
__global__ __launch_bounds__(256) void wconv_kernel(
    const float* __restrict__ w0, const float* __restrict__ w1,
    const float* __restrict__ w2, const float* __restrict__ w3,
    u16* __restrict__ wt) {
  __shared__ __align__(16) u16 tile[64][65];
  int which = blockIdx.z;
  const float* W = (which == 0) ? w0 : (which == 1) ? w1 : (which == 2) ? w2 : w3;
  u16* WT = wt + (size_t)which * CDIM * CDIM;
  int kb = blockIdx.x * 64, nb = blockIdx.y * 64;
  int t = threadIdx.x;
#pragma unroll
  for (int i = 0; i < 16; ++i) {
    int idx = t + i * 256;
    int r = idx >> 6, c = idx & 63;
    tile[r][c] = f2bf(W[(size_t)(kb + r) * CDIM + nb + c]);
  }
  __syncthreads();
#pragma unroll
  for (int i = 0; i < 16; ++i) {
    int idx = t + i * 256;
    int r = idx >> 6, c = idx & 63;
    WT[(size_t)(nb + r) * CDIM + kb + c] = tile[c][r];
  }
}

// ---------------- bf16 v [BN, C] -> vt [B, C, N] ----------------
__global__ __launch_bounds__(256) void vtrans_kernel(const u16* __restrict__ v,
                                                     u16* __restrict__ vt) {
  __shared__ __align__(16) u16 tile[64][65];
  int nb = blockIdx.x * 64;
  int cb = blockIdx.y * 64;
  int b = blockIdx.z;
  int t = threadIdx.x;
  const u16* src = v + ((size_t)b * NTOK + nb) * CDIM + cb;
#pragma unroll
  for (int i = 0; i < 16; ++i) {
    int idx = t + i * 256;
    int r = idx >> 6, c = idx & 63;
    tile[r][c] = src[(size_t)r * CDIM + c];
  }
  __syncthreads();
  u16* dst = vt + ((size_t)b * CDIM + cb) * NTOK + nb;
#pragma unroll
  for (int i = 0; i < 16; ++i) {
    int idx = t + i * 256;
    int r = idx >> 6, c = idx & 63;
    dst[(size_t)r * NTOK + c] = tile[c][r];
  }
}

// ------- GEMM out[m,n] = sum_k A[m,k]*Bt[n,k] (+bias)(xscale | +res) -------
// MODE 0: bf16 store of (acc+bias)*scale ; MODE 1: f32 store of acc+bias+res
template <int MODE>
__global__ __launch_bounds__(256) void gemm_kernel(
    const u16* __restrict__ A, const u16* __restrict__ Bt,
    const float* __restrict__ bias, const float* __restrict__ res,
    void* __restrict__ outp, float scale) {
  __shared__ __align__(16) u16 Als[128 * 32];
  __shared__ __align__(16) u16 Bls[128 * 32];
  int t = threadIdx.x;
  int w = t >> 6, lane = t & 63;
  int lr = lane & 15, lg = lane >> 4;
  int wr = w >> 1, wc = w & 1;
  int mbase = blockIdx.y * 128, nbase = blockIdx.x * 128;
  const f32x4 fz = {0.f, 0.f, 0.f, 0.f};
  f32x4 acc[4][4];
#pragma unroll
  for (int m = 0; m < 4; ++m)
#pragma unroll
    for (int n = 0; n < 4; ++n) acc[m][n] = fz;

  const u16* ga0 = A + (size_t)(mbase + (t >> 2)) * CDIM + (t & 3) * 8;
  const u16* gb0 = Bt + (size_t)(nbase + (t >> 2)) * CDIM + (t & 3) * 8;
  u16* la = Als + w * 512;
  u16* lb = Bls + w * 512;

  for (int kt = 0; kt < CDIM / 32; ++kt) {
    __syncthreads();
    int ko = kt * 32;
    gload16(ga0 + ko, la);
    gload16(ga0 + (size_t)64 * CDIM + ko, la + 2048);
    gload16(gb0 + ko, lb);
    gload16(gb0 + (size_t)64 * CDIM + ko, lb + 2048);
    __syncthreads();
    short8 af[4], bfr[4];
#pragma unroll
    for (int m = 0; m < 4; ++m)
      af[m] = *(const short8*)(Als + (wr * 64 + m * 16 + lr) * 32 + lg * 8);
#pragma unroll
    for (int n = 0; n < 4; ++n)
      bfr[n] = *(const short8*)(Bls + (wc * 64 + n * 16 + lr) * 32 + lg * 8);
#pragma unroll
    for (int m = 0; m < 4; ++m)
#pragma unroll
      for (int n = 0; n < 4; ++n)
        acc[m][n] = mfma16(af[m], bfr[n], acc[m][n]);
  }

#pragma unroll
  for (int m = 0; m < 4; ++m) {
    int grow = mbase + wr * 64 + m * 16 + lg * 4;
#pragma unroll
    for (int n = 0; n < 4; ++n) {
      int gcol = nbase + wc * 64 + n * 16 + lr;
      float bnc = bias[gcol];
#pragma unroll
      for (int r = 0; r < 4; ++r) {
        size_t idx = (size_t)(grow + r) * CDIM + gcol;
        float val = acc[m][n][r] + bnc;
        if (MODE == 0) {
          ((u16*)outp)[idx] = f2bf(val * scale);
        } else {
          ((float*)outp)[idx] = val + res[idx];
        }
      }
    }
  }
}

// ---------------- flash attention: q,k [B,N,C], vt [B,C,N] -> o [B,N,C] ----
__global__ __launch_bounds__(256, 1) void flash_kernel(
    const u16* __restrict__ q, const u16* __restrict__ k,
    const u16* __restrict__ vt, u16* __restrict__ o) {
  int b = blockIdx.y;
  int w = threadIdx.x >> 6;
  int lane = threadIdx.x & 63;
  int lr = lane & 15, lg = lane >> 4;
  int qbase = blockIdx.x * 64 + w * 16;
  const u16* Q = q + ((size_t)b * NTOK + qbase) * CDIM;
  const u16* K = k + (size_t)b * NTOK * CDIM;
  const u16* VT = vt + (size_t)b * CDIM * NTOK;

  short8 aq[16];
#pragma unroll
  for (int ks = 0; ks < 16; ++ks)
    aq[ks] = *(const short8*)(Q + (size_t)lr * CDIM + ks * 32 + lg * 8);

  const f32x4 fz = {0.f, 0.f, 0.f, 0.f};
  f32x4 acc[32];
#pragma unroll
  for (int n = 0; n < 32; ++n) acc[n] = fz;
  float m_run[4] = {-1e30f, -1e30f, -1e30f, -1e30f};
  float l_run[4] = {0.f, 0.f, 0.f, 0.f};

  __shared__ __align__(16) u16 Plds[4][16 * 32];
  u16* pw = &Plds[w][0];

  for (int kv = 0; kv < NTOK; kv += 32) {
    const u16* K0 = K + (size_t)(kv + lr) * CDIM + lg * 8;
    const u16* K1 = K0 + (size_t)16 * CDIM;
    f32x4 s0 = fz, s1 = fz;
#pragma unroll
    for (int ks = 0; ks < 16; ++ks) {
      short8 b0 = *(const short8*)(K0 + ks * 32);
      short8 b1 = *(const short8*)(K1 + ks * 32);
      s0 = mfma16(aq[ks], b0, s0);
      s1 = mfma16(aq[ks], b1, s1);
    }
    float pmax[4], alpha[4], psum[4];
#pragma unroll
    for (int r = 0; r < 4; ++r) pmax[r] = fmaxf(s0[r], s1[r]);
#pragma unroll
    for (int j = 0; j < 4; ++j)
#pragma unroll
      for (int r = 0; r < 4; ++r)
        pmax[r] = fmaxf(pmax[r], __shfl_xor(pmax[r], 1 << j));
#pragma unroll
    for (int r = 0; r < 4; ++r) {
      float mnew = fmaxf(m_run[r], pmax[r]);
      alpha[r] = __expf(m_run[r] - mnew);
      m_run[r] = mnew;
      float p0 = __expf(s0[r] - mnew);
      float p1 = __expf(s1[r] - mnew);
      psum[r] = p0 + p1;
      pw[(lg * 4 + r) * 32 + lr] = f2bf(p0);
      pw[(lg * 4 + r) * 32 + 16 + lr] = f2bf(p1);
    }
#pragma unroll
    for (int j = 0; j < 4; ++j)
#pragma unroll
      for (int r = 0; r < 4; ++r) psum[r] += __shfl_xor(psum[r], 1 << j);
#pragma unroll
    for (int r = 0; r < 4; ++r) l_run[r] = l_run[r] * alpha[r] + psum[r];
#pragma unroll
    for (int n = 0; n < 32; ++n)
#pragma unroll
      for (int r = 0; r < 4; ++r) acc[n][r] *= alpha[r];
    short8 pa = *(const short8*)(pw + lr * 32 + lg * 8);
    const u16* Vb = VT + (size_t)lr * NTOK + kv + lg * 8;
#pragma unroll
    for (int n = 0; n < 32; ++n) {
      short8 bv = *(const short8*)(Vb + (size_t)(n * 16) * NTOK);
      acc[n] = mfma16(pa, bv, acc[n]);
    }
  }
  float inv[4];
#pragma unroll
  for (int r = 0; r < 4; ++r) inv[r] = 1.0f / l_run[r];
  u16* O = o + ((size_t)b * NTOK + qbase) * CDIM;
#pragma unroll
  for (int n = 0; n < 32; ++n)
#pragma unroll
    for (int r = 0; r < 4; ++r)
      O[(size_t)(lg * 4 + r) * CDIM + n * 16 + lr] = f2bf(acc[n][r] * inv[r]);
}

extern "C" void kernel_launch(void* const* d_in, const int* in_sizes, int n_in,
                              void* d_out, int out_size, void* d_ws, size_t ws_size,
                              hipStream_t stream) {
  (void)in_sizes; (void)n_in; (void)out_size; (void)ws_size;
  const float* x    = (const float*)d_in[0];
  const float* ln_g = (const float*)d_in[1];
  const float* ln_b = (const float*)d_in[2];
  const float* Wq   = (const float*)d_in[3];
  const float* bq   = (const float*)d_in[4];
  const float* Wk   = (const float*)d_in[5];
  const float* bk   = (const float*)d_in[6];
  const float* Wv   = (const float*)d_in[7];
  const float* bv   = (const float*)d_in[8];
  const float* Wp   = (const float*)d_in[9];
  const float* bp   = (const float*)d_in[10];

  const size_t SEG = (size_t)NROWS * CDIM * 2;  // 16 MB per bf16 [BN,C] buffer
  char* ws = (char*)d_ws;
  u16* hn  = (u16*)(ws + 0 * SEG);
  u16* qb  = (u16*)(ws + 1 * SEG);
  u16* kbf = (u16*)(ws + 2 * SEG);
  u16* vb  = (u16*)(ws + 3 * SEG);
  u16* ob  = (u16*)(ws + 4 * SEG);
  u16* wt  = (u16*)(ws + 5 * SEG);
  u16* vt  = hn;  // hn dead after the three projections; reuse for V^T

  hipLaunchKernelGGL(wconv_kernel, dim3(8, 8, 4), dim3(256), 0, stream,
                     Wq, Wk, Wv, Wp, wt);
  hipLaunchKernelGGL(ln_kernel, dim3(NROWS / 4), dim3(256), 0, stream,
                     x, ln_g, ln_b, hn);
  const float qscale = 0.0441941738241592f;  // 1/sqrt(512)
  hipLaunchKernelGGL((gemm_kernel<0>), dim3(4, 128), dim3(256), 0, stream,
                     hn, wt + 0 * CDIM * CDIM, bq, (const float*)nullptr,
                     (void*)qb, qscale);
  hipLaunchKernelGGL((gemm_kernel<0>), dim3(4, 128), dim3(256), 0, stream,
                     hn, wt + 1 * CDIM * CDIM, bk, (const float*)nullptr,
                     (void*)kbf, 1.0f);
  hipLaunchKernelGGL((gemm_kernel<0>), dim3(4, 128), dim3(256), 0, stream,
                     hn, wt + 2 * CDIM * CDIM, bv, (const float*)nullptr,
                     (void*)vb, 1.0f);
  hipLaunchKernelGGL(vtrans_kernel, dim3(64, 8, 4), dim3(256), 0, stream, vb, vt);
  hipLaunchKernelGGL(flash_kernel, dim3(64, 4), dim3(256), 0, stream,
                     qb, kbf, vt, ob);
  hipLaunchKernelGGL((gemm_kernel<1>), dim3(4, 128), dim3(256), 0, stream,
                     ob, wt + 3 * CDIM * CDIM, bp, x, d_out, 1.0f);
}

// Round 2
// 372.227 us; speedup vs baseline: 4.3821x; 4.3821x over previous
//
#include <hip/hip_runtime.h>
#include <cstdint>
#include <cmath>

typedef unsigned short u16;
typedef __attribute__((ext_vector_type(8))) short short8;
typedef __attribute__((ext_vector_type(4))) float f32x4;

#define BB 4
#define NTOK 4096
#define CDIM 512
#define NROWS (BB * NTOK)

__device__ __forceinline__ u16 f2bf(float f) {
  union { float f; uint32_t u; } v; v.f = f;
  return (u16)((v.u + 0x7fffu + ((v.u >> 16) & 1u)) >> 16);
}

__device__ __forceinline__ float bf2f(u16 u) {
  union { uint32_t u; float f; } v; v.u = (uint32_t)u << 16;
  return v.f;
}

__device__ __forceinline__ f32x4 mfma16(short8 a, short8 b, f32x4 c) {
  return __builtin_amdgcn_mfma_f32_16x16x32_bf16(a, b, c, 0, 0, 0);
}

__device__ __forceinline__ void gload16(const u16* g, u16* l) {
  __builtin_amdgcn_global_load_lds(
      (const __attribute__((address_space(1))) void*)g,
      (__attribute__((address_space(3))) void*)l, 16, 0, 0);
}

// ---------------- LayerNorm (one wave per row of 512) ----------------
__global__ __launch_bounds__(256) void ln_kernel(const float* __restrict__ x,
                                                 const float* __restrict__ gam,
                                                 const float* __restrict__ bet,
                                                 u16* __restrict__ hn) {
  int row = blockIdx.x * 4 + (threadIdx.x >> 6);
  int lane = threadIdx.x & 63;
  const float4* xr = (const float4*)(x + (size_t)row * CDIM);
  float4 a0 = xr[lane];
  float4 a1 = xr[lane + 64];
  float s = a0.x + a0.y + a0.z + a0.w + a1.x + a1.y + a1.z + a1.w;
  float ss = a0.x * a0.x + a0.y * a0.y + a0.z * a0.z + a0.w * a0.w +
             a1.x * a1.x + a1.y * a1.y + a1.z * a1.z + a1.w * a1.w;
#pragma unroll
  for (int j = 0; j < 6; ++j) {
    s += __shfl_xor(s, 1 << j);
    ss += __shfl_xor(ss, 1 << j);
  }
  float mu = s * (1.0f / CDIM);
  float var = ss * (1.0f / CDIM) - mu * mu;
  float rs = rsqrtf(var + 1e-3f);
  const float4* g4 = (const float4*)gam;
  const float4* b4 = (const float4*)bet;
  float4 g0 = g4[lane], g1 = g4[lane + 64];
  float4 c0 = b4[lane], c1 = b4[lane + 64];
  u16* out = hn + (size_t)row * CDIM;
  ushort4 o0, o1;
  o0.x = f2bf((a0.x - mu) * rs * g0.x + c0.x);
  o0.y = f2bf((a0.y - mu) * rs * g0.y + c0.y);
  o0.z = f2bf((a0.z - mu) * rs * g0.z + c0.z);
  o0.w = f2bf((a0.w - mu) * rs * g0.w + c0.w);
  o1.x = f2bf((a1.x - mu) * rs * g1.x + c1.x);
  o1.y = f2bf((a1.y - mu) * rs * g1.y + c1.y);
  o1.z = f2bf((a1.z - mu) * rs * g1.z + c1.z);
  o1.w = f2bf((a1.w - mu) * rs * g1.w + c1.w);
  *(ushort4*)(out + lane * 4) = o0;
  *(ushort4*)(out + 256 + lane * 4) = o1;
}

// ---------- weights: fp32 [K,N] -> bf16 W^T [N,K], 4 of them ----------
__global__ __launch_bounds__(256) void wconv_kernel(
    const float* __restrict__ w0, const float* __restrict__ w1,
    const float* __restrict__ w2, const float* __restrict__ w3,
    u16* __restrict__ wt) {
  __shared__ __align__(16) u16 tile[64][65];
  int which = blockIdx.z;
  const float* W = (which == 0) ? w0 : (which == 1) ? w1 : (which == 2) ? w2 : w3;
  u16* WT = wt + (size_t)which * CDIM * CDIM;
  int kb = blockIdx.x * 64, nb = blockIdx.y * 64;
  int t = threadIdx.x;
#pragma unroll
  for (int i = 0; i < 16; ++i) {
    int idx = t + i * 256;
    int r = idx >> 6, c = idx & 63;
    tile[r][c] = f2bf(W[(size_t)(kb + r) * CDIM + nb + c]);
  }
  __syncthreads();
#pragma unroll
  for (int i = 0; i < 16; ++i) {
    int idx = t + i * 256;
    int r = idx >> 6, c = idx & 63;
    WT[(size_t)(nb + r) * CDIM + kb + c] = tile[c][r];
  }
}

// ---------------- bf16 v [BN, C] -> vt [B, C, N] ----------------
__global__ __launch_bounds__(256) void vtrans_kernel(const u16* __restrict__ v,
                                                     u16* __restrict__ vt) {
  __shared__ __align__(16) u16 tile[64][65];
  int nb = blockIdx.x * 64;
  int cb = blockIdx.y * 64;
  int b = blockIdx.z;
  int t = threadIdx.x;
  const u16* src = v + ((size_t)b * NTOK + nb) * CDIM + cb;
#pragma unroll
  for (int i = 0; i < 16; ++i) {
    int idx = t + i * 256;
    int r = idx >> 6, c = idx & 63;
    tile[r][c] = src[(size_t)r * CDIM + c];
  }
  __syncthreads();
  u16* dst = vt + ((size_t)b * CDIM + cb) * NTOK + nb;
#pragma unroll
  for (int i = 0; i < 16; ++i) {
    int idx = t + i * 256;
    int r = idx >> 6, c = idx & 63;
    dst[(size_t)r * NTOK + c] = tile[c][r];
  }
}

// ---- generalized GEMM: out[m,n] = sum_k A[m,k] * Bt[n,k], batched via z ----
// MODE 0: bf16 store (acc+bias)*scale        (projections)
// MODE 1: f32  store acc+bias+res            (final output)
// MODE 2: bf16 store acc                     (QK^T scores)
// MODE 3: bf16 store acc * (1/lsum[row])     (PV with softmax normalize)
template <int MODE>
__global__ __launch_bounds__(256) void gemm_kernel(
    const u16* __restrict__ A, int lda, size_t az,
    const u16* __restrict__ Bt, int ldb, size_t bz,
    const float* __restrict__ bias, const float* __restrict__ res,
    const float* __restrict__ lsum, int lz,
    void* __restrict__ outp, int ldo, size_t oz,
    int K, float scale) {
  __shared__ __align__(16) u16 Als[128 * 32];
  __shared__ __align__(16) u16 Bls[128 * 32];
  int t = threadIdx.x;
  int w = t >> 6, lane = t & 63;
  int lr = lane & 15, lg = lane >> 4;
  int wr = w >> 1, wc = w & 1;
  int z = blockIdx.z;
  int mbase = blockIdx.y * 128, nbase = blockIdx.x * 128;
  const u16* Az = A + az * (size_t)z;
  const u16* Bz = Bt + bz * (size_t)z;
  const f32x4 fz = {0.f, 0.f, 0.f, 0.f};
  f32x4 acc[4][4];
#pragma unroll
  for (int m = 0; m < 4; ++m)
#pragma unroll
    for (int n = 0; n < 4; ++n) acc[m][n] = fz;

  const u16* ga0 = Az + (size_t)(mbase + (t >> 2)) * lda + (t & 3) * 8;
  const u16* gb0 = Bz + (size_t)(nbase + (t >> 2)) * ldb + (t & 3) * 8;
  u16* la = Als + w * 512;
  u16* lb = Bls + w * 512;

  for (int kt = 0; kt < (K >> 5); ++kt) {
    __syncthreads();
    int ko = kt * 32;
    gload16(ga0 + ko, la);
    gload16(ga0 + (size_t)64 * lda + ko, la + 2048);
    gload16(gb0 + ko, lb);
    gload16(gb0 + (size_t)64 * ldb + ko, lb + 2048);
    __syncthreads();
    short8 af[4], bfr[4];
#pragma unroll
    for (int m = 0; m < 4; ++m)
      af[m] = *(const short8*)(Als + (wr * 64 + m * 16 + lr) * 32 + lg * 8);
#pragma unroll
    for (int n = 0; n < 4; ++n)
      bfr[n] = *(const short8*)(Bls + (wc * 64 + n * 16 + lr) * 32 + lg * 8);
#pragma unroll
    for (int m = 0; m < 4; ++m)
#pragma unroll
      for (int n = 0; n < 4; ++n)
        acc[m][n] = mfma16(af[m], bfr[n], acc[m][n]);
  }

#pragma unroll
  for (int m = 0; m < 4; ++m) {
    int grow = mbase + wr * 64 + m * 16 + lg * 4;
    float rl[4];
    if (MODE == 3) {
#pragma unroll
      for (int r = 0; r < 4; ++r)
        rl[r] = 1.0f / lsum[(size_t)lz * z + grow + r];
    }
#pragma unroll
    for (int n = 0; n < 4; ++n) {
      int gcol = nbase + wc * 64 + n * 16 + lr;
      float bnc = (MODE == 0 || MODE == 1) ? bias[gcol] : 0.f;
#pragma unroll
      for (int r = 0; r < 4; ++r) {
        size_t idx = (size_t)(grow + r) * ldo + gcol;
        float val = acc[m][n][r];
        if (MODE == 0) {
          ((u16*)outp + oz * (size_t)z)[idx] = f2bf((val + bnc) * scale);
        } else if (MODE == 1) {
          ((float*)outp)[idx] = val + bnc + res[idx];
        } else if (MODE == 2) {
          ((u16*)outp + oz * (size_t)z)[idx] = f2bf(val);
        } else {
          ((u16*)outp + oz * (size_t)z)[idx] = f2bf(val * rl[r]);
        }
      }
    }
  }
}

// ---- softmax over rows of 4096 bf16, in-place, one wave per row ----
__global__ __launch_bounds__(256) void softmax_kernel(u16* __restrict__ S,
                                                      float* __restrict__ lsum) {
  int row = blockIdx.x * 4 + (threadIdx.x >> 6);
  int lane = threadIdx.x & 63;
  u16* Sr = S + (size_t)row * NTOK;
  short8 d[8];
#pragma unroll
  for (int i = 0; i < 8; ++i)
    d[i] = *(const short8*)(Sr + i * 512 + lane * 8);
  float mx = -1e30f;
#pragma unroll
  for (int i = 0; i < 8; ++i)
#pragma unroll
    for (int j = 0; j < 8; ++j) mx = fmaxf(mx, bf2f((u16)d[i][j]));
#pragma unroll
  for (int j = 0; j < 6; ++j) mx = fmaxf(mx, __shfl_xor(mx, 1 << j));
  float sum = 0.f;
#pragma unroll
  for (int i = 0; i < 8; ++i) {
    short8 o;
#pragma unroll
    for (int j = 0; j < 8; ++j) {
      float p = __expf(bf2f((u16)d[i][j]) - mx);
      sum += p;
      o[j] = (short)f2bf(p);
    }
    *(short8*)(Sr + i * 512 + lane * 8) = o;
  }
#pragma unroll
  for (int j = 0; j < 6; ++j) sum += __shfl_xor(sum, 1 << j);
  if (lane == 0) lsum[row] = sum;
}

extern "C" void kernel_launch(void* const* d_in, const int* in_sizes, int n_in,
                              void* d_out, int out_size, void* d_ws, size_t ws_size,
                              hipStream_t stream) {
  (void)in_sizes; (void)n_in; (void)out_size;
  const float* x    = (const float*)d_in[0];
  const float* ln_g = (const float*)d_in[1];
  const float* ln_b = (const float*)d_in[2];
  const float* Wq   = (const float*)d_in[3];
  const float* bq   = (const float*)d_in[4];
  const float* Wk   = (const float*)d_in[5];
  const float* bk   = (const float*)d_in[6];
  const float* Wv   = (const float*)d_in[7];
  const float* bv   = (const float*)d_in[8];
  const float* Wp   = (const float*)d_in[9];
  const float* bp   = (const float*)d_in[10];

  const size_t MB = 1024ull * 1024ull;
  char* ws = (char*)d_ws;
  u16* wt   = (u16*)(ws);             // 2 MB: 4 transposed bf16 weights
  float* ls = (float*)(ws + 2 * MB);  // 64 KB row sums (slot 2 MB)
  u16* hn   = (u16*)(ws + 4 * MB);    // 16 MB (reused as ob after projections)
  u16* qb   = (u16*)(ws + 20 * MB);   // 16 MB
  u16* kbf  = (u16*)(ws + 36 * MB);   // 16 MB
  u16* vt   = (u16*)(ws + 52 * MB);   // 16 MB
  u16* vb   = (u16*)(ws + 68 * MB);   // 16 MB (dead after vtrans)
  bool full = ws_size >= 212 * MB;
  u16* S    = full ? (u16*)(ws + 84 * MB) : vb;  // 128 MB : 32 MB overlay
  u16* ob   = hn;

  hipLaunchKernelGGL(wconv_kernel, dim3(8, 8, 4), dim3(256), 0, stream,
                     Wq, Wk, Wv, Wp, wt);
  hipLaunchKernelGGL(ln_kernel, dim3(NROWS / 4), dim3(256), 0, stream,
                     x, ln_g, ln_b, hn);
  const float qscale = 0.0441941738241592f;  // 1/sqrt(512)
  // projections: [16384,512] x [512,512]
  hipLaunchKernelGGL((gemm_kernel<0>), dim3(4, 128, 1), dim3(256), 0, stream,
                     hn, CDIM, (size_t)0, wt + 0 * CDIM * CDIM, CDIM, (size_t)0,
                     bq, (const float*)nullptr, (const float*)nullptr, 0,
                     (void*)qb, CDIM, (size_t)0, CDIM, qscale);
  hipLaunchKernelGGL((gemm_kernel<0>), dim3(4, 128, 1), dim3(256), 0, stream,
                     hn, CDIM, (size_t)0, wt + 1 * CDIM * CDIM, CDIM, (size_t)0,
                     bk, (const float*)nullptr, (const float*)nullptr, 0,
                     (void*)kbf, CDIM, (size_t)0, CDIM, 1.0f);
  hipLaunchKernelGGL((gemm_kernel<0>), dim3(4, 128, 1), dim3(256), 0, stream,
                     hn, CDIM, (size_t)0, wt + 2 * CDIM * CDIM, CDIM, (size_t)0,
                     bv, (const float*)nullptr, (const float*)nullptr, 0,
                     (void*)vb, CDIM, (size_t)0, CDIM, 1.0f);
  hipLaunchKernelGGL(vtrans_kernel, dim3(64, 8, 4), dim3(256), 0, stream, vb, vt);

  int nz = full ? 4 : 1;
  int np = full ? 1 : 4;
  for (int p = 0; p < np; ++p) {
    const u16* qp  = qb + (size_t)p * NTOK * CDIM;
    const u16* kp  = kbf + (size_t)p * NTOK * CDIM;
    const u16* vtp = vt + (size_t)p * CDIM * NTOK;
    u16* obp = ob + (size_t)p * NTOK * CDIM;
    float* lp = ls + (size_t)p * NTOK;
    // S = Q K^T  (scores, bf16): M=N=4096, K=512 per batch
    hipLaunchKernelGGL((gemm_kernel<2>), dim3(32, 32, nz), dim3(256), 0, stream,
                       qp, CDIM, (size_t)NTOK * CDIM, kp, CDIM, (size_t)NTOK * CDIM,
                       (const float*)nullptr, (const float*)nullptr,
                       (const float*)nullptr, 0,
                       (void*)S, NTOK, (size_t)NTOK * NTOK, CDIM, 1.0f);
    // softmax rows (in-place) + row sums
    hipLaunchKernelGGL(softmax_kernel, dim3(nz * NTOK / 4), dim3(256), 0, stream,
                       S, lp);
    // O = P V (normalized by 1/l): M=4096, N=512, K=4096 per batch
    hipLaunchKernelGGL((gemm_kernel<3>), dim3(4, 32, nz), dim3(256), 0, stream,
                       S, NTOK, (size_t)NTOK * NTOK, vtp, NTOK, (size_t)CDIM * NTOK,
                       (const float*)nullptr, (const float*)nullptr, lp, NTOK,
                       (void*)obp, CDIM, (size_t)NTOK * CDIM, NTOK, 1.0f);
  }
  // final: out = O Wp + bp + x  (f32)
  hipLaunchKernelGGL((gemm_kernel<1>), dim3(4, 128, 1), dim3(256), 0, stream,
                     ob, CDIM, (size_t)0, wt + 3 * CDIM * CDIM, CDIM, (size_t)0,
                     bp, x, (const float*)nullptr, 0,
                     d_out, CDIM, (size_t)0, CDIM, 1.0f);
}

// Round 3
// 359.181 us; speedup vs baseline: 4.5413x; 1.0363x over previous
//
#include <hip/hip_runtime.h>
#include <cstdint>
#include <cmath>

typedef unsigned short u16;
typedef __attribute__((ext_vector_type(8))) short short8;
typedef __attribute__((ext_vector_type(4))) float f32x4;

#define BB 4
#define NTOK 4096
#define CDIM 512
#define NROWS (BB * NTOK)

__device__ __forceinline__ u16 f2bf(float f) {
  union { float f; uint32_t u; } v; v.f = f;
  return (u16)((v.u + 0x7fffu + ((v.u >> 16) & 1u)) >> 16);
}

__device__ __forceinline__ float bf2f(u16 u) {
  union { uint32_t u; float f; } v; v.u = (uint32_t)u << 16;
  return v.f;
}

__device__ __forceinline__ f32x4 mfma16(short8 a, short8 b, f32x4 c) {
  return __builtin_amdgcn_mfma_f32_16x16x32_bf16(a, b, c, 0, 0, 0);
}

__device__ __forceinline__ void gload16(const u16* g, u16* l) {
  __builtin_amdgcn_global_load_lds(
      (const __attribute__((address_space(1))) void*)g,
      (__attribute__((address_space(3))) void*)l, 16, 0, 0);
}

// ---------------- LayerNorm (one wave per row of 512) ----------------
__global__ __launch_bounds__(256) void ln_kernel(const float* __restrict__ x,
                                                 const float* __restrict__ gam,
                                                 const float* __restrict__ bet,
                                                 u16* __restrict__ hn) {
  int row = blockIdx.x * 4 + (threadIdx.x >> 6);
  int lane = threadIdx.x & 63;
  const float4* xr = (const float4*)(x + (size_t)row * CDIM);
  float4 a0 = xr[lane];
  float4 a1 = xr[lane + 64];
  float s = a0.x + a0.y + a0.z + a0.w + a1.x + a1.y + a1.z + a1.w;
  float ss = a0.x * a0.x + a0.y * a0.y + a0.z * a0.z + a0.w * a0.w +
             a1.x * a1.x + a1.y * a1.y + a1.z * a1.z + a1.w * a1.w;
#pragma unroll
  for (int j = 0; j < 6; ++j) {
    s += __shfl_xor(s, 1 << j);
    ss += __shfl_xor(ss, 1 << j);
  }
  float mu = s * (1.0f / CDIM);
  float var = ss * (1.0f / CDIM) - mu * mu;
  float rs = rsqrtf(var + 1e-3f);
  const float4* g4 = (const float4*)gam;
  const float4* b4 = (const float4*)bet;
  float4 g0 = g4[lane], g1 = g4[lane + 64];
  float4 c0 = b4[lane], c1 = b4[lane + 64];
  u16* out = hn + (size_t)row * CDIM;
  ushort4 o0, o1;
  o0.x = f2bf((a0.x - mu) * rs * g0.x + c0.x);
  o0.y = f2bf((a0.y - mu) * rs * g0.y + c0.y);
  o0.z = f2bf((a0.z - mu) * rs * g0.z + c0.z);
  o0.w = f2bf((a0.w - mu) * rs * g0.w + c0.w);
  o1.x = f2bf((a1.x - mu) * rs * g1.x + c1.x);
  o1.y = f2bf((a1.y - mu) * rs * g1.y + c1.y);
  o1.z = f2bf((a1.z - mu) * rs * g1.z + c1.z);
  o1.w = f2bf((a1.w - mu) * rs * g1.w + c1.w);
  *(ushort4*)(out + lane * 4) = o0;
  *(ushort4*)(out + 256 + lane * 4) = o1;
}

// ---------- weights: fp32 [K,N] -> bf16 W^T [N,K], 4 of them ----------
__global__ __launch_bounds__(256) void wconv_kernel(
    const float* __restrict__ w0, const float* __restrict__ w1,
    const float* __restrict__ w2, const float* __restrict__ w3,
    u16* __restrict__ wt) {
  __shared__ __align__(16) u16 tile[64][65];
  int which = blockIdx.z;
  const float* W = (which == 0) ? w0 : (which == 1) ? w1 : (which == 2) ? w2 : w3;
  u16* WT = wt + (size_t)which * CDIM * CDIM;
  int kb = blockIdx.x * 64, nb = blockIdx.y * 64;
  int t = threadIdx.x;
#pragma unroll
  for (int i = 0; i < 16; ++i) {
    int idx = t + i * 256;
    int r = idx >> 6, c = idx & 63;
    tile[r][c] = f2bf(W[(size_t)(kb + r) * CDIM + nb + c]);
  }
  __syncthreads();
#pragma unroll
  for (int i = 0; i < 16; ++i) {
    int idx = t + i * 256;
    int r = idx >> 6, c = idx & 63;
    WT[(size_t)(nb + r) * CDIM + kb + c] = tile[c][r];
  }
}

// ---------------- bf16 v [BN, C] -> vt [B, C, N] ----------------
__global__ __launch_bounds__(256) void vtrans_kernel(const u16* __restrict__ v,
                                                     u16* __restrict__ vt) {
  __shared__ __align__(16) u16 tile[64][65];
  int nb = blockIdx.x * 64;
  int cb = blockIdx.y * 64;
  int b = blockIdx.z;
  int t = threadIdx.x;
  const u16* src = v + ((size_t)b * NTOK + nb) * CDIM + cb;
#pragma unroll
  for (int i = 0; i < 16; ++i) {
    int idx = t + i * 256;
    int r = idx >> 6, c = idx & 63;
    tile[r][c] = src[(size_t)r * CDIM + c];
  }
  __syncthreads();
  u16* dst = vt + ((size_t)b * CDIM + cb) * NTOK + nb;
#pragma unroll
  for (int i = 0; i < 16; ++i) {
    int idx = t + i * 256;
    int r = idx >> 6, c = idx & 63;
    dst[(size_t)r * NTOK + c] = tile[c][r];
  }
}

// ---- generalized GEMM: out[m,n] = sum_k A[m,k] * Bt[n,k], batched via z ----
// Prefetch 2-phase: STAGE(next) issued before compute(cur); one barrier/K-step.
// LDS frag-read 2-way-swizzled (slot ^= (row&3)^((row>>2)&1)); global source
// pre-swizzled to match linear global_load_lds dest (rule #21).
// MODE 0: bf16 store (acc+bias)*scale        (projections)
// MODE 1: f32  store acc+bias+res            (final output)
// MODE 2: bf16 store acc                     (QK^T scores)
// MODE 3: bf16 store acc * (1/lsum[row])     (PV with softmax normalize)
// KSPLIT: z = batch*2 + khalf; khalf offsets A/B k-dim by K, out by koz.
template <int MODE, int KSPLIT>
__global__ __launch_bounds__(256) void gemm_kernel(
    const u16* __restrict__ A, int lda, size_t az,
    const u16* __restrict__ Bt, int ldb, size_t bz,
    const float* __restrict__ bias, const float* __restrict__ res,
    const float* __restrict__ lsum, int lz,
    void* __restrict__ outp, int ldo, size_t oz, size_t koz,
    int K, float scale) {
  __shared__ __align__(16) u16 Als[2][128 * 32];
  __shared__ __align__(16) u16 Bls[2][128 * 32];
  int t = threadIdx.x;
  int w = t >> 6, lane = t & 63;
  int lr = lane & 15, lg = lane >> 4;
  int wr = w >> 1, wc = w & 1;
  int z = blockIdx.z;
  size_t aoff, boff, ooff;
  int lsrow0;
  if (KSPLIT) {
    int batch = z >> 1, kh = z & 1;
    aoff = az * (size_t)batch + (size_t)kh * K;
    boff = bz * (size_t)batch + (size_t)kh * K;
    ooff = oz * (size_t)batch + koz * (size_t)kh;
    lsrow0 = lz * batch;
  } else {
    aoff = az * (size_t)z; boff = bz * (size_t)z; ooff = oz * (size_t)z;
    lsrow0 = lz * z;
  }
  int mbase = blockIdx.y * 128, nbase = blockIdx.x * 128;
  const f32x4 fz = {0.f, 0.f, 0.f, 0.f};
  f32x4 acc[4][4];
#pragma unroll
  for (int m = 0; m < 4; ++m)
#pragma unroll
    for (int n = 0; n < 4; ++n) acc[m][n] = fz;

  // staging: thread t -> LDS elems [t*8, t*8+8) = row t>>2, slot t&3 (linear).
  // physical slot s holds logical col-slot s ^ f(row), f = (row&3)^((row>>2)&1)
  int scol = (((t & 3) ^ ((t >> 2) & 3) ^ ((t >> 4) & 1)) * 8);
  const u16* ga0 = A + aoff + (size_t)(mbase + (t >> 2)) * lda + scol;
  const u16* gb0 = Bt + boff + (size_t)(nbase + (t >> 2)) * ldb + scol;
  int rsA = (lg ^ (lr & 3) ^ ((lr >> 2) & 1)) * 8;  // swizzled read slot*8

#define STAGE(buf, ko)                                          \
  {                                                             \
    gload16(ga0 + (ko), &Als[buf][w * 512]);                    \
    gload16(ga0 + (size_t)64 * lda + (ko), &Als[buf][w * 512 + 2048]); \
    gload16(gb0 + (ko), &Bls[buf][w * 512]);                    \
    gload16(gb0 + (size_t)64 * ldb + (ko), &Bls[buf][w * 512 + 2048]); \
  }

  int nk = K >> 5;
  STAGE(0, 0);
  __syncthreads();
  int cur = 0;
  for (int kt = 0; kt < nk; ++kt) {
    if (kt + 1 < nk) STAGE(cur ^ 1, (kt + 1) * 32);
    short8 af[4], bfr[4];
#pragma unroll
    for (int m = 0; m < 4; ++m)
      af[m] = *(const short8*)(&Als[cur][(wr * 64 + m * 16 + lr) * 32 + rsA]);
#pragma unroll
    for (int n = 0; n < 4; ++n)
      bfr[n] = *(const short8*)(&Bls[cur][(wc * 64 + n * 16 + lr) * 32 + rsA]);
#pragma unroll
    for (int m = 0; m < 4; ++m)
#pragma unroll
      for (int n = 0; n < 4; ++n)
        acc[m][n] = mfma16(af[m], bfr[n], acc[m][n]);
    __syncthreads();
    cur ^= 1;
  }
#undef STAGE

#pragma unroll
  for (int m = 0; m < 4; ++m) {
    int grow = mbase + wr * 64 + m * 16 + lg * 4;
    float rl[4];
    if (MODE == 3) {
#pragma unroll
      for (int r = 0; r < 4; ++r)
        rl[r] = 1.0f / lsum[lsrow0 + grow + r];
    }
#pragma unroll
    for (int n = 0; n < 4; ++n) {
      int gcol = nbase + wc * 64 + n * 16 + lr;
      float bnc = (MODE == 0 || MODE == 1) ? bias[gcol] : 0.f;
#pragma unroll
      for (int r = 0; r < 4; ++r) {
        size_t idx = (size_t)(grow + r) * ldo + gcol;
        float val = acc[m][n][r];
        if (MODE == 0) {
          ((u16*)outp + ooff)[idx] = f2bf((val + bnc) * scale);
        } else if (MODE == 1) {
          ((float*)outp)[idx] = val + bnc + res[idx];
        } else if (MODE == 2) {
          ((u16*)outp + ooff)[idx] = f2bf(val);
        } else {
          ((u16*)outp + ooff)[idx] = f2bf(val * rl[r]);
        }
      }
    }
  }
}

// ---- softmax over rows of 4096 bf16, in-place, one wave per row ----
__global__ __launch_bounds__(256) void softmax_kernel(u16* __restrict__ S,
                                                      float* __restrict__ lsum) {
  int row = blockIdx.x * 4 + (threadIdx.x >> 6);
  int lane = threadIdx.x & 63;
  u16* Sr = S + (size_t)row * NTOK;
  short8 d[8];
#pragma unroll
  for (int i = 0; i < 8; ++i)
    d[i] = *(const short8*)(Sr + i * 512 + lane * 8);
  float mx = -1e30f;
#pragma unroll
  for (int i = 0; i < 8; ++i)
#pragma unroll
    for (int j = 0; j < 8; ++j) mx = fmaxf(mx, bf2f((u16)d[i][j]));
#pragma unroll
  for (int j = 0; j < 6; ++j) mx = fmaxf(mx, __shfl_xor(mx, 1 << j));
  float sum = 0.f;
#pragma unroll
  for (int i = 0; i < 8; ++i) {
    short8 o;
#pragma unroll
    for (int j = 0; j < 8; ++j) {
      float p = __expf(bf2f((u16)d[i][j]) - mx);
      sum += p;
      o[j] = (short)f2bf(p);
    }
    *(short8*)(Sr + i * 512 + lane * 8) = o;
  }
#pragma unroll
  for (int j = 0; j < 6; ++j) sum += __shfl_xor(sum, 1 << j);
  if (lane == 0) lsum[row] = sum;
}

// ---- sum two bf16 partial buffers -> bf16 ----
__global__ __launch_bounds__(256) void addp_kernel(const u16* __restrict__ p0,
                                                   const u16* __restrict__ p1,
                                                   u16* __restrict__ ob) {
  size_t i = ((size_t)blockIdx.x * 256 + threadIdx.x) * 8;
  short8 a = *(const short8*)(p0 + i);
  short8 b = *(const short8*)(p1 + i);
  short8 o;
#pragma unroll
  for (int j = 0; j < 8; ++j)
    o[j] = (short)f2bf(bf2f((u16)a[j]) + bf2f((u16)b[j]));
  *(short8*)(ob + i) = o;
}

extern "C" void kernel_launch(void* const* d_in, const int* in_sizes, int n_in,
                              void* d_out, int out_size, void* d_ws, size_t ws_size,
                              hipStream_t stream) {
  (void)in_sizes; (void)n_in; (void)out_size;
  const float* x    = (const float*)d_in[0];
  const float* ln_g = (const float*)d_in[1];
  const float* ln_b = (const float*)d_in[2];
  const float* Wq   = (const float*)d_in[3];
  const float* bq   = (const float*)d_in[4];
  const float* Wk   = (const float*)d_in[5];
  const float* bk   = (const float*)d_in[6];
  const float* Wv   = (const float*)d_in[7];
  const float* bv   = (const float*)d_in[8];
  const float* Wp   = (const float*)d_in[9];
  const float* bp   = (const float*)d_in[10];

  const size_t MB = 1024ull * 1024ull;
  char* ws = (char*)d_ws;
  u16* wt   = (u16*)(ws);             // 2 MB: 4 transposed bf16 weights
  float* ls = (float*)(ws + 2 * MB);  // 64 KB row sums (slot 2 MB)
  u16* hn   = (u16*)(ws + 4 * MB);    // 16 MB (reused as ob after projections)
  u16* qb   = (u16*)(ws + 20 * MB);   // 16 MB (reused as PV partial0)
  u16* kbf  = (u16*)(ws + 36 * MB);   // 16 MB (reused as PV partial1)
  u16* vt   = (u16*)(ws + 52 * MB);   // 16 MB
  u16* vb   = (u16*)(ws + 68 * MB);   // 16 MB (dead after vtrans)
  bool full = ws_size >= 212 * MB;
  u16* S    = full ? (u16*)(ws + 84 * MB) : vb;  // 128 MB : 32 MB overlay
  u16* ob   = hn;
  // non-full: per-batch partials above the 32 MB S overlay
  u16* p0nf = (u16*)(ws + 100 * MB);
  u16* p1nf = (u16*)(ws + 104 * MB);

  const float* nullf = nullptr;

  hipLaunchKernelGGL(wconv_kernel, dim3(8, 8, 4), dim3(256), 0, stream,
                     Wq, Wk, Wv, Wp, wt);
  hipLaunchKernelGGL(ln_kernel, dim3(NROWS / 4), dim3(256), 0, stream,
                     x, ln_g, ln_b, hn);
  const float qscale = 0.0441941738241592f;  // 1/sqrt(512)
  // projections: [16384,512] x [512,512]
  hipLaunchKernelGGL((gemm_kernel<0, 0>), dim3(4, 128, 1), dim3(256), 0, stream,
                     hn, CDIM, (size_t)0, wt + 0 * CDIM * CDIM, CDIM, (size_t)0,
                     bq, nullf, nullf, 0,
                     (void*)qb, CDIM, (size_t)0, (size_t)0, CDIM, qscale);
  hipLaunchKernelGGL((gemm_kernel<0, 0>), dim3(4, 128, 1), dim3(256), 0, stream,
                     hn, CDIM, (size_t)0, wt + 1 * CDIM * CDIM, CDIM, (size_t)0,
                     bk, nullf, nullf, 0,
                     (void*)kbf, CDIM, (size_t)0, (size_t)0, CDIM, 1.0f);
  hipLaunchKernelGGL((gemm_kernel<0, 0>), dim3(4, 128, 1), dim3(256), 0, stream,
                     hn, CDIM, (size_t)0, wt + 2 * CDIM * CDIM, CDIM, (size_t)0,
                     bv, nullf, nullf, 0,
                     (void*)vb, CDIM, (size_t)0, (size_t)0, CDIM, 1.0f);
  hipLaunchKernelGGL(vtrans_kernel, dim3(64, 8, 4), dim3(256), 0, stream, vb, vt);

  if (full) {
    // S = Q K^T : M=N=4096, K=512, z=4 batches
    hipLaunchKernelGGL((gemm_kernel<2, 0>), dim3(32, 32, 4), dim3(256), 0, stream,
                       qb, CDIM, (size_t)NTOK * CDIM, kbf, CDIM, (size_t)NTOK * CDIM,
                       nullf, nullf, nullf, 0,
                       (void*)S, NTOK, (size_t)NTOK * NTOK, (size_t)0, CDIM, 1.0f);
    hipLaunchKernelGGL(softmax_kernel, dim3(4 * NTOK / 4), dim3(256), 0, stream,
                       S, ls);
    // O = P V, split-K=2: z = batch*2 + khalf, partials -> qb (p0) / kbf (p1)
    hipLaunchKernelGGL((gemm_kernel<3, 1>), dim3(4, 32, 8), dim3(256), 0, stream,
                       S, NTOK, (size_t)NTOK * NTOK, vt, NTOK, (size_t)CDIM * NTOK,
                       nullf, nullf, ls, NTOK,
                       (void*)qb, CDIM, (size_t)NTOK * CDIM,
                       (size_t)NROWS * CDIM, NTOK / 2, 1.0f);
    hipLaunchKernelGGL(addp_kernel, dim3(NROWS * CDIM / 2048), dim3(256), 0,
                       stream, qb, kbf, ob);
  } else {
    for (int p = 0; p < 4; ++p) {
      const u16* qp  = qb + (size_t)p * NTOK * CDIM;
      const u16* kp  = kbf + (size_t)p * NTOK * CDIM;
      const u16* vtp = vt + (size_t)p * CDIM * NTOK;
      u16* obp = ob + (size_t)p * NTOK * CDIM;
      float* lp = ls + (size_t)p * NTOK;
      hipLaunchKernelGGL((gemm_kernel<2, 0>), dim3(32, 32, 1), dim3(256), 0, stream,
                         qp, CDIM, (size_t)0, kp, CDIM, (size_t)0,
                         nullf, nullf, nullf, 0,
                         (void*)S, NTOK, (size_t)0, (size_t)0, CDIM, 1.0f);
      hipLaunchKernelGGL(softmax_kernel, dim3(NTOK / 4), dim3(256), 0, stream,
                         S, lp);
      hipLaunchKernelGGL((gemm_kernel<3, 1>), dim3(4, 32, 2), dim3(256), 0, stream,
                         S, NTOK, (size_t)0, vtp, NTOK, (size_t)0,
                         nullf, nullf, lp, NTOK,
                         (void*)p0nf, CDIM, (size_t)0,
                         (size_t)NTOK * CDIM, NTOK / 2, 1.0f);
      hipLaunchKernelGGL(addp_kernel, dim3(NTOK * CDIM / 2048), dim3(256), 0,
                         stream, p0nf, p1nf, obp);
    }
  }
  // final: out = O Wp + bp + x  (f32)
  hipLaunchKernelGGL((gemm_kernel<1, 0>), dim3(4, 128, 1), dim3(256), 0, stream,
                     ob, CDIM, (size_t)0, wt + 3 * CDIM * CDIM, CDIM, (size_t)0,
                     bp, x, nullf, 0,
                     d_out, CDIM, (size_t)0, (size_t)0, CDIM, 1.0f);
}

// Round 4
// 345.495 us; speedup vs baseline: 4.7212x; 1.0396x over previous
//
#include <hip/hip_runtime.h>
#include <cstdint>
#include <cmath>

typedef unsigned short u16;
typedef __attribute__((ext_vector_type(8))) short short8;
typedef __attribute__((ext_vector_type(4))) float f32x4;

#define BB 4
#define NTOK 4096
#define CDIM 512
#define NROWS (BB * NTOK)
#define QSCALE 0.0441941738241592f  // 1/sqrt(512)

__device__ __forceinline__ u16 f2bf(float f) {
  union { float f; uint32_t u; } v; v.f = f;
  return (u16)((v.u + 0x7fffu + ((v.u >> 16) & 1u)) >> 16);
}

__device__ __forceinline__ float bf2f(u16 u) {
  union { uint32_t u; float f; } v; v.u = (uint32_t)u << 16;
  return v.f;
}

__device__ __forceinline__ f32x4 mfma16(short8 a, short8 b, f32x4 c) {
  return __builtin_amdgcn_mfma_f32_16x16x32_bf16(a, b, c, 0, 0, 0);
}

__device__ __forceinline__ void gload16(const u16* g, u16* l) {
  __builtin_amdgcn_global_load_lds(
      (const __attribute__((address_space(1))) void*)g,
      (__attribute__((address_space(3))) void*)l, 16, 0, 0);
}

// ---------------- LayerNorm (one wave per row of 512) ----------------
__global__ __launch_bounds__(256) void ln_kernel(const float* __restrict__ x,
                                                 const float* __restrict__ gam,
                                                 const float* __restrict__ bet,
                                                 u16* __restrict__ hn) {
  int row = blockIdx.x * 4 + (threadIdx.x >> 6);
  int lane = threadIdx.x & 63;
  const float4* xr = (const float4*)(x + (size_t)row * CDIM);
  float4 a0 = xr[lane];
  float4 a1 = xr[lane + 64];
  float s = a0.x + a0.y + a0.z + a0.w + a1.x + a1.y + a1.z + a1.w;
  float ss = a0.x * a0.x + a0.y * a0.y + a0.z * a0.z + a0.w * a0.w +
             a1.x * a1.x + a1.y * a1.y + a1.z * a1.z + a1.w * a1.w;
#pragma unroll
  for (int j = 0; j < 6; ++j) {
    s += __shfl_xor(s, 1 << j);
    ss += __shfl_xor(ss, 1 << j);
  }
  float mu = s * (1.0f / CDIM);
  float var = ss * (1.0f / CDIM) - mu * mu;
  float rs = rsqrtf(var + 1e-3f);
  const float4* g4 = (const float4*)gam;
  const float4* b4 = (const float4*)bet;
  float4 g0 = g4[lane], g1 = g4[lane + 64];
  float4 c0 = b4[lane], c1 = b4[lane + 64];
  u16* out = hn + (size_t)row * CDIM;
  ushort4 o0, o1;
  o0.x = f2bf((a0.x - mu) * rs * g0.x + c0.x);
  o0.y = f2bf((a0.y - mu) * rs * g0.y + c0.y);
  o0.z = f2bf((a0.z - mu) * rs * g0.z + c0.z);
  o0.w = f2bf((a0.w - mu) * rs * g0.w + c0.w);
  o1.x = f2bf((a1.x - mu) * rs * g1.x + c1.x);
  o1.y = f2bf((a1.y - mu) * rs * g1.y + c1.y);
  o1.z = f2bf((a1.z - mu) * rs * g1.z + c1.z);
  o1.w = f2bf((a1.w - mu) * rs * g1.w + c1.w);
  *(ushort4*)(out + lane * 4) = o0;
  *(ushort4*)(out + 256 + lane * 4) = o1;
}

// -- weights fp32 [K,N] -> bf16 W^T rows [Q|K|V|P] [2048,512]; Q pre-scaled.
// -- also builds concatenated scaled bias bqkv[1536].
__global__ __launch_bounds__(256) void wconv_kernel(
    const float* __restrict__ w0, const float* __restrict__ w1,
    const float* __restrict__ w2, const float* __restrict__ w3,
    const float* __restrict__ bq, const float* __restrict__ bk,
    const float* __restrict__ bv,
    u16* __restrict__ wt, float* __restrict__ bqkv) {
  __shared__ __align__(16) u16 tile[64][65];
  int which = blockIdx.z;
  const float* W = (which == 0) ? w0 : (which == 1) ? w1 : (which == 2) ? w2 : w3;
  float wscale = (which == 0) ? QSCALE : 1.0f;
  u16* WT = wt + (size_t)which * CDIM * CDIM;
  int kb = blockIdx.x * 64, nb = blockIdx.y * 64;
  int t = threadIdx.x;
  if (kb == 0 && which < 3 && t < 64) {
    const float* bs = (which == 0) ? bq : (which == 1) ? bk : bv;
    bqkv[which * CDIM + nb + t] = bs[nb + t] * wscale;
  }
#pragma unroll
  for (int i = 0; i < 16; ++i) {
    int idx = t + i * 256;
    int r = idx >> 6, c = idx & 63;
    tile[r][c] = f2bf(W[(size_t)(kb + r) * CDIM + nb + c] * wscale);
  }
  __syncthreads();
#pragma unroll
  for (int i = 0; i < 16; ++i) {
    int idx = t + i * 256;
    int r = idx >> 6, c = idx & 63;
    WT[(size_t)(nb + r) * CDIM + kb + c] = tile[c][r];
  }
}

// ------- bf16 src [BN, ld] (col window 64) -> vt [B, C, N] transpose -------
__global__ __launch_bounds__(256) void vtrans_kernel(const u16* __restrict__ v,
                                                     int ld,
                                                     u16* __restrict__ vt) {
  __shared__ __align__(16) u16 tile[64][65];
  int nb = blockIdx.x * 64;
  int cb = blockIdx.y * 64;
  int b = blockIdx.z;
  int t = threadIdx.x;
  const u16* src = v + ((size_t)b * NTOK + nb) * ld + cb;
#pragma unroll
  for (int i = 0; i < 16; ++i) {
    int idx = t + i * 256;
    int r = idx >> 6, c = idx & 63;
    tile[r][c] = src[(size_t)r * ld + c];
  }
  __syncthreads();
  u16* dst = vt + ((size_t)b * CDIM + cb) * NTOK + nb;
#pragma unroll
  for (int i = 0; i < 16; ++i) {
    int idx = t + i * 256;
    int r = idx >> 6, c = idx & 63;
    dst[(size_t)r * NTOK + c] = tile[c][r];
  }
}

// ---- generalized GEMM: out[m,n] = sum_k A[m,k] * Bt[n,k], batched via z ----
// Depth-2 counted-vmcnt pipeline: raw s_barrier, per-wave s_waitcnt vmcnt(4)
// keeps next tile's 4 global_load_lds in flight across the barrier (T4).
// MODE 0: bf16 store acc+bias                (fused QKV projection)
// MODE 1: f32  store acc+bias+res            (final output)
// MODE 2: bf16 store acc                     (QK^T scores)
// MODE 3: bf16 store acc * (1/lsum[row])     (PV with softmax normalize)
// KSPLIT: z = batch*2 + khalf; khalf offsets A/B k-dim by K, out by koz.
template <int MODE, int KSPLIT>
__global__ __launch_bounds__(256) void gemm_kernel(
    const u16* __restrict__ A, int lda, size_t az,
    const u16* __restrict__ Bt, int ldb, size_t bz,
    const float* __restrict__ bias, const float* __restrict__ res,
    const float* __restrict__ lsum, int lz,
    void* __restrict__ outp, int ldo, size_t oz, size_t koz,
    int K) {
  __shared__ __align__(16) u16 Als[2][128 * 32];
  __shared__ __align__(16) u16 Bls[2][128 * 32];
  int t = threadIdx.x;
  int w = t >> 6, lane = t & 63;
  int lr = lane & 15, lg = lane >> 4;
  int wr = w >> 1, wc = w & 1;
  int z = blockIdx.z;
  size_t aoff, boff, ooff;
  int lsrow0;
  if (KSPLIT) {
    int batch = z >> 1, kh = z & 1;
    aoff = az * (size_t)batch + (size_t)kh * K;
    boff = bz * (size_t)batch + (size_t)kh * K;
    ooff = oz * (size_t)batch + koz * (size_t)kh;
    lsrow0 = lz * batch;
  } else {
    aoff = az * (size_t)z; boff = bz * (size_t)z; ooff = oz * (size_t)z;
    lsrow0 = lz * z;
  }
  int mbase = blockIdx.y * 128, nbase = blockIdx.x * 128;
  const f32x4 fz = {0.f, 0.f, 0.f, 0.f};
  f32x4 acc[4][4];
#pragma unroll
  for (int m = 0; m < 4; ++m)
#pragma unroll
    for (int n = 0; n < 4; ++n) acc[m][n] = fz;

  // staging: thread t -> LDS elems [t*8, t*8+8) (linear dest for gload_lds);
  // global source pre-swizzled so physical slot s holds logical slot
  // s ^ f(row), f = (row&3)^((row>>2)&1)  (rule #21: both-sides-or-neither)
  int scol = (((t & 3) ^ ((t >> 2) & 3) ^ ((t >> 4) & 1)) * 8);
  const u16* ga0 = A + aoff + (size_t)(mbase + (t >> 2)) * lda + scol;
  const u16* gb0 = Bt + boff + (size_t)(nbase + (t >> 2)) * ldb + scol;
  int rsA = (lg ^ (lr & 3) ^ ((lr >> 2) & 1)) * 8;  // swizzled read slot*8

#define STAGE(buf, ko)                                                 \
  {                                                                    \
    gload16(ga0 + (ko), &Als[buf][w * 512]);                           \
    gload16(ga0 + (size_t)64 * lda + (ko), &Als[buf][w * 512 + 2048]); \
    gload16(gb0 + (ko), &Bls[buf][w * 512]);                           \
    gload16(gb0 + (size_t)64 * ldb + (ko), &Bls[buf][w * 512 + 2048]); \
  }

  int nk = K >> 5;  // nk >= 2 always here
  STAGE(0, 0);
  STAGE(1, 32);
  int cur = 0;
  for (int kt = 0; kt < nk; ++kt) {
    // certify my own tile-kt loads done (leave tile kt+1's 4 in flight),
    // then barrier makes all waves' tile-kt LDS writes visible.
    if (kt + 1 < nk) {
      asm volatile("s_waitcnt vmcnt(4)" ::: "memory");
    } else {
      asm volatile("s_waitcnt vmcnt(0)" ::: "memory");
    }
    __builtin_amdgcn_s_barrier();
    asm volatile("" ::: "memory");          // IR fence: no ds_read hoist
    __builtin_amdgcn_sched_barrier(0);      // MIR fence (rule #18)
    short8 af[4], bfr[4];
#pragma unroll
    for (int m = 0; m < 4; ++m)
      af[m] = *(const short8*)(&Als[cur][(wr * 64 + m * 16 + lr) * 32 + rsA]);
#pragma unroll
    for (int n = 0; n < 4; ++n)
      bfr[n] = *(const short8*)(&Bls[cur][(wc * 64 + n * 16 + lr) * 32 + rsA]);
#pragma unroll
    for (int m = 0; m < 4; ++m)
#pragma unroll
      for (int n = 0; n < 4; ++n)
        acc[m][n] = mfma16(af[m], bfr[n], acc[m][n]);
    // my ds_reads retired; barrier => safe for anyone to overwrite buf[cur]
    asm volatile("s_waitcnt lgkmcnt(0)" ::: "memory");
    __builtin_amdgcn_s_barrier();
    asm volatile("" ::: "memory");
    if (kt + 2 < nk) STAGE(cur, (kt + 2) * 32);
    cur ^= 1;
  }
#undef STAGE

#pragma unroll
  for (int m = 0; m < 4; ++m) {
    int grow = mbase + wr * 64 + m * 16 + lg * 4;
    float rl[4];
    if (MODE == 3) {
#pragma unroll
      for (int r = 0; r < 4; ++r)
        rl[r] = 1.0f / lsum[lsrow0 + grow + r];
    }
#pragma unroll
    for (int n = 0; n < 4; ++n) {
      int gcol = nbase + wc * 64 + n * 16 + lr;
      float bnc = (MODE == 0 || MODE == 1) ? bias[gcol] : 0.f;
#pragma unroll
      for (int r = 0; r < 4; ++r) {
        size_t idx = (size_t)(grow + r) * ldo + gcol;
        float val = acc[m][n][r];
        if (MODE == 0) {
          ((u16*)outp + ooff)[idx] = f2bf(val + bnc);
        } else if (MODE == 1) {
          ((float*)outp)[idx] = val + bnc + res[idx];
        } else if (MODE == 2) {
          ((u16*)outp + ooff)[idx] = f2bf(val);
        } else {
          ((u16*)outp + ooff)[idx] = f2bf(val * rl[r]);
        }
      }
    }
  }
}

// ---- softmax over rows of 4096 bf16, in-place, one wave per row ----
__global__ __launch_bounds__(256) void softmax_kernel(u16* __restrict__ S,
                                                      float* __restrict__ lsum) {
  int row = blockIdx.x * 4 + (threadIdx.x >> 6);
  int lane = threadIdx.x & 63;
  u16* Sr = S + (size_t)row * NTOK;
  short8 d[8];
#pragma unroll
  for (int i = 0; i < 8; ++i)
    d[i] = *(const short8*)(Sr + i * 512 + lane * 8);
  float mx = -1e30f;
#pragma unroll
  for (int i = 0; i < 8; ++i)
#pragma unroll
    for (int j = 0; j < 8; ++j) mx = fmaxf(mx, bf2f((u16)d[i][j]));
#pragma unroll
  for (int j = 0; j < 6; ++j) mx = fmaxf(mx, __shfl_xor(mx, 1 << j));
  float sum = 0.f;
#pragma unroll
  for (int i = 0; i < 8; ++i) {
    short8 o;
#pragma unroll
    for (int j = 0; j < 8; ++j) {
      float p = __expf(bf2f((u16)d[i][j]) - mx);
      sum += p;
      o[j] = (short)f2bf(p);
    }
    *(short8*)(Sr + i * 512 + lane * 8) = o;
  }
#pragma unroll
  for (int j = 0; j < 6; ++j) sum += __shfl_xor(sum, 1 << j);
  if (lane == 0) lsum[row] = sum;
}

// ---- sum two bf16 partial buffers -> bf16 ----
__global__ __launch_bounds__(256) void addp_kernel(const u16* __restrict__ p0,
                                                   const u16* __restrict__ p1,
                                                   u16* __restrict__ ob) {
  size_t i = ((size_t)blockIdx.x * 256 + threadIdx.x) * 8;
  short8 a = *(const short8*)(p0 + i);
  short8 b = *(const short8*)(p1 + i);
  short8 o;
#pragma unroll
  for (int j = 0; j < 8; ++j)
    o[j] = (short)f2bf(bf2f((u16)a[j]) + bf2f((u16)b[j]));
  *(short8*)(ob + i) = o;
}

extern "C" void kernel_launch(void* const* d_in, const int* in_sizes, int n_in,
                              void* d_out, int out_size, void* d_ws, size_t ws_size,
                              hipStream_t stream) {
  (void)in_sizes; (void)n_in; (void)out_size;
  const float* x    = (const float*)d_in[0];
  const float* ln_g = (const float*)d_in[1];
  const float* ln_b = (const float*)d_in[2];
  const float* Wq   = (const float*)d_in[3];
  const float* bq   = (const float*)d_in[4];
  const float* Wk   = (const float*)d_in[5];
  const float* bk   = (const float*)d_in[6];
  const float* Wv   = (const float*)d_in[7];
  const float* bv   = (const float*)d_in[8];
  const float* Wp   = (const float*)d_in[9];
  const float* bp   = (const float*)d_in[10];

  const size_t MB = 1024ull * 1024ull;
  const size_t KB = 1024ull;
  char* ws = (char*)d_ws;
  u16* wt     = (u16*)(ws);                  // 2 MB: [Q|K|V|P] W^T bf16
  float* bqkv = (float*)(ws + 2 * MB);       // 6 KB concat scaled bias
  float* ls   = (float*)(ws + 2 * MB + 64 * KB);  // 64 KB row sums
  u16* hn     = (u16*)(ws + 4 * MB);         // 16 MB (reused as ob)
  u16* qkv    = (u16*)(ws + 20 * MB);        // 48 MB [16384,1536]
  u16* vt     = (u16*)(ws + 68 * MB);        // 16 MB
  bool full = ws_size >= 212 * MB;
  u16* S    = (u16*)(ws + 84 * MB);          // 128 MB (full) / 32 MB (fallback)
  // PV partials: full path -> qkv region (dead by then); fallback -> above S
  u16* p0   = full ? qkv : (u16*)(ws + 116 * MB);
  u16* p1   = p0 + (full ? (size_t)NROWS * CDIM : (size_t)NTOK * CDIM);
  u16* ob   = hn;

  const float* nullf = nullptr;

  hipLaunchKernelGGL(wconv_kernel, dim3(8, 8, 4), dim3(256), 0, stream,
                     Wq, Wk, Wv, Wp, bq, bk, bv, wt, bqkv);
  hipLaunchKernelGGL(ln_kernel, dim3(NROWS / 4), dim3(256), 0, stream,
                     x, ln_g, ln_b, hn);
  // fused QKV projection: [16384,512] x [1536,512]^T -> qkv [16384,1536]
  hipLaunchKernelGGL((gemm_kernel<0, 0>), dim3(12, 128, 1), dim3(256), 0, stream,
                     hn, CDIM, (size_t)0, wt, CDIM, (size_t)0,
                     bqkv, nullf, nullf, 0,
                     (void*)qkv, 3 * CDIM, (size_t)0, (size_t)0, CDIM);
  // V columns of qkv -> vt [B, C, N]
  hipLaunchKernelGGL(vtrans_kernel, dim3(64, 8, 4), dim3(256), 0, stream,
                     qkv + 2 * CDIM, 3 * CDIM, vt);

  if (full) {
    // S = Q K^T : M=N=4096, K=512, z=4 batches (Q,K column-slices of qkv)
    hipLaunchKernelGGL((gemm_kernel<2, 0>), dim3(32, 32, 4), dim3(256), 0, stream,
                       qkv, 3 * CDIM, (size_t)NTOK * 3 * CDIM,
                       qkv + CDIM, 3 * CDIM, (size_t)NTOK * 3 * CDIM,
                       nullf, nullf, nullf, 0,
                       (void*)S, NTOK, (size_t)NTOK * NTOK, (size_t)0, CDIM);
    hipLaunchKernelGGL(softmax_kernel, dim3(4 * NTOK / 4), dim3(256), 0, stream,
                       S, ls);
    // O = P V, split-K=2: z = batch*2 + khalf; partials p0/p1 (qkv dead now)
    hipLaunchKernelGGL((gemm_kernel<3, 1>), dim3(4, 32, 8), dim3(256), 0, stream,
                       S, NTOK, (size_t)NTOK * NTOK, vt, NTOK, (size_t)CDIM * NTOK,
                       nullf, nullf, ls, NTOK,
                       (void*)p0, CDIM, (size_t)NTOK * CDIM,
                       (size_t)NROWS * CDIM, NTOK / 2);
    hipLaunchKernelGGL(addp_kernel, dim3(NROWS * CDIM / 2048), dim3(256), 0,
                       stream, p0, p1, ob);
  } else {
    for (int p = 0; p < 4; ++p) {
      const u16* qp  = qkv + (size_t)p * NTOK * 3 * CDIM;
      const u16* kp  = qp + CDIM;
      const u16* vtp = vt + (size_t)p * CDIM * NTOK;
      u16* obp = ob + (size_t)p * NTOK * CDIM;
      float* lp = ls + (size_t)p * NTOK;
      hipLaunchKernelGGL((gemm_kernel<2, 0>), dim3(32, 32, 1), dim3(256), 0, stream,
                         qp, 3 * CDIM, (size_t)0, kp, 3 * CDIM, (size_t)0,
                         nullf, nullf, nullf, 0,
                         (void*)S, NTOK, (size_t)0, (size_t)0, CDIM);
      hipLaunchKernelGGL(softmax_kernel, dim3(NTOK / 4), dim3(256), 0, stream,
                         S, lp);
      hipLaunchKernelGGL((gemm_kernel<3, 1>), dim3(4, 32, 2), dim3(256), 0, stream,
                         S, NTOK, (size_t)0, vtp, NTOK, (size_t)0,
                         nullf, nullf, lp, 0,
                         (void*)p0, CDIM, (size_t)0, (size_t)NTOK * CDIM,
                         NTOK / 2);
      hipLaunchKernelGGL(addp_kernel, dim3(NTOK * CDIM / 2048), dim3(256), 0,
                         stream, p0, p1, obp);
    }
  }
  // final: out = O Wp + bp + x  (f32)
  hipLaunchKernelGGL((gemm_kernel<1, 0>), dim3(4, 128, 1), dim3(256), 0, stream,
                     ob, CDIM, (size_t)0, wt + 3 * CDIM * CDIM, CDIM, (size_t)0,
                     bp, x, nullf, 0,
                     d_out, CDIM, (size_t)0, (size_t)0, CDIM);
}